// Round 10
// baseline (1466.349 us; speedup 1.0000x reference)
//
#include <hip/hip_runtime.h>

#define N_ENTITIES 200000
#define N_ITEMS    100000
#define DIM        64
#define N_EDGES    1500000
#define K_EDGES    256
#define K_ITEMS    100
// 1 / (2 * sqrt(32))  (mean over 2 heads of per-head 1/sqrt(Dk))
#define SCALE      0.08838834764831845f

#define CAND_CAP   8192
#define NB1        256       // level-1 bucket virtual blocks
#define EPB        5860      // edges per virtual block (256*5860 >= 1.5M)
#define NBUCK      782       // head>>8 buckets
#define NSC        (NBUCK * NB1)
#define L2CAP      2816      // max edges per bucket (mean 1918 + 20 sigma)

typedef unsigned long long u64;

// NOTE (round-0): fp16/bf16 storage of proj is FORBIDDEN (ordered top-100 item
// list; adjacent gaps ~8e-6; fp16 error 2.7e-6 -> rank flips). f32 only.
// NOTE (rounds 3-8, atomic saga): gfx950 global atomics execute memory-side
// regardless of scope/sc-bits. NON-RETURNING atomics are FREE (r7). RETURNING
// global atomics drain ~50ns each (1.5M = ~75us, 5 implementations). Ranks
// belong in LDS atomics (cheap).
// NOTE (r8): edge-centric is traffic-bound 467MB @ ~2.9TB/s = 160us. r9's
// node-major CSR (atomic-free two-level bucket sort) = 293MB @ 3.0TB/s = 99us
// in node_pass -- the random-gather BW ceiling (~3TB/s) seen in BOTH shapes.
// NOTE (r9): visible kernels sum to ~215us of 437 -> ~150-200us lives in the
// 12 dispatch boundaries (launch + drain + L2 flush). This round: ONE
// persistent kernel with hand-rolled grid barriers (3 dispatches total).
// Barrier = agent-scope atomics + fence release/acquire (the same cache
// maintenance a dispatch boundary pays). Grid = occupancy-query x CUs so all
// blocks are co-resident; every phase is grid-stride.

// ---- monotonic float<->u32 key (order-preserving, total order) ----
__device__ __forceinline__ unsigned fkey(float x) {
    unsigned u = __float_as_uint(x);
    return (u & 0x80000000u) ? ~u : (u | 0x80000000u);
}
__device__ __forceinline__ float funkey(unsigned k) {
    return (k & 0x80000000u) ? __uint_as_float(k & 0x7fffffffu)
                             : __uint_as_float(~k);
}

// serial 256-bin select: largest bin b with count(>b) < Keff <= count(>=b).
__device__ __forceinline__ unsigned select_digit(const unsigned* __restrict__ hist,
                                                 unsigned Keff, unsigned* above) {
    unsigned cum = 0;
    int b = 255;
    for (; b > 0; --b) {
        unsigned hb = hist[b];
        if (cum + hb >= Keff) break;
        cum += hb;
    }
    *above = cum;
    return (unsigned)b;
}

// ---- grid barrier: generation-counter, agent scope. All blocks co-resident
// (grid sized by occupancy query). Release fence publishes our stores
// (L2 writeback); acquire fence invalidates stale lines on exit.
__device__ __forceinline__ void gbar(unsigned* bar) {
    __syncthreads();
    if (threadIdx.x == 0) {
        __builtin_amdgcn_fence(__ATOMIC_RELEASE, "agent");
        unsigned gen = __hip_atomic_load(&bar[1], __ATOMIC_RELAXED, __HIP_MEMORY_SCOPE_AGENT);
        unsigned a = __hip_atomic_fetch_add(&bar[0], 1u, __ATOMIC_RELAXED, __HIP_MEMORY_SCOPE_AGENT);
        if (a == gridDim.x - 1) {
            __hip_atomic_store(&bar[0], 0u, __ATOMIC_RELAXED, __HIP_MEMORY_SCOPE_AGENT);
            __hip_atomic_store(&bar[1], gen + 1u, __ATOMIC_RELAXED, __HIP_MEMORY_SCOPE_AGENT);
        } else {
            unsigned long long spins = 0;
            while (__hip_atomic_load(&bar[1], __ATOMIC_RELAXED, __HIP_MEMORY_SCOPE_AGENT) == gen) {
                __builtin_amdgcn_s_sleep(2);
                if (++spins > 60000000ull) break;   // ~seconds; fail visibly, never hang
            }
        }
        __builtin_amdgcn_fence(__ATOMIC_ACQUIRE, "agent");
    }
    __syncthreads();
}

// ---- proj = emb @ W_Q. Pure GEMM, separate launch (register-heavy phase
// kept out of the mega-kernel so it can't crush its occupancy). ----
__global__ __launch_bounds__(256) void proj_kernel(const float* __restrict__ emb,
                                                   const float* __restrict__ W,
                                                   float* __restrict__ proj) {
    __shared__ float part[4][16][64];
    const int t = threadIdx.x;
    const int c = t & 63;
    const int q = __builtin_amdgcn_readfirstlane(t >> 6);

    float Wreg[16];
#pragma unroll
    for (int j = 0; j < 16; ++j) Wreg[j] = W[(q * 16 + j) * 64 + c];

    const int base = blockIdx.x * 16;   // 200000 = 12500 * 16, exact
    const float* erow = emb + (size_t)base * 64 + q * 16;

    float acc[16];
#pragma unroll
    for (int r = 0; r < 16; ++r) acc[r] = 0.f;
#pragma unroll
    for (int r = 0; r < 16; ++r) {
#pragma unroll
        for (int j = 0; j < 16; ++j)
            acc[r] += erow[r * 64 + j] * Wreg[j];
    }
#pragma unroll
    for (int r = 0; r < 16; ++r) part[q][r][c] = acc[r];
    __syncthreads();
#pragma unroll
    for (int it = 0; it < 4; ++it) {
        int oi = t + it * 256;
        int r = oi >> 6, cc = oi & 63;
        float s = part[0][r][cc] + part[1][r][cc] + part[2][r][cc] + part[3][r][cc];
        proj[(size_t)(base + r) * 64 + cc] = s;
    }
}

// ---- the whole rest of the pipeline: 9 phases, 8 grid barriers ----
__global__ __launch_bounds__(256) void mega_kernel(
    const int* __restrict__ head, const int* __restrict__ tailp,
    const int* __restrict__ etype,
    const float4* __restrict__ proj4, const float4* __restrict__ rel4,
    const float* __restrict__ noise_u,
    unsigned* __restrict__ off, unsigned* __restrict__ rowtot,
    u64* __restrict__ rec2, u64* __restrict__ rec3,
    unsigned* __restrict__ start, unsigned* __restrict__ degtot,
    float* __restrict__ logits, float2* __restrict__ nd,
    float* __restrict__ sumhead, float* __restrict__ sumI,
    float* __restrict__ out_scores,
    unsigned* __restrict__ keysE, unsigned* __restrict__ keysI,
    unsigned* __restrict__ hists, unsigned* __restrict__ counters,
    unsigned* __restrict__ cand,
    float* __restrict__ out_topkv, float* __restrict__ out_topki,
    float* __restrict__ out_itemv, float* __restrict__ out_itemi,
    unsigned* __restrict__ bar)
{
    __shared__ unsigned smem[1920];   // 7.68KB union for all phases
    const int t = threadIdx.x;
    const int G = gridDim.x;

    // ---- P1: level-1 bucket histogram (virtual blocks over NB1) ----
    for (int vb = blockIdx.x; vb < NB1; vb += G) {
        for (int j = t; j < NBUCK; j += 256) smem[j] = 0;
        __syncthreads();
        int base = vb * EPB;
        int end = base + EPB; if (end > N_EDGES) end = N_EDGES;
        for (int e = base + t; e < end; e += 256)
            atomicAdd(&smem[(unsigned)head[e] >> 8], 1u);   // LDS atomic: cheap
        __syncthreads();
        for (int j = t; j < NBUCK; j += 256)
            off[(size_t)j * NB1 + vb] = smem[j];
        __syncthreads();
    }
    gbar(bar);

    // ---- P2: row-local exclusive scans (one 256-wide row per iteration) ----
    for (int k = blockIdx.x; k < NBUCK; k += G) {
        unsigned v = off[(size_t)k * NB1 + t];
        smem[t] = v;
        __syncthreads();
        for (int o = 1; o < 256; o <<= 1) {
            unsigned x = smem[t];
            unsigned y = (t >= o) ? smem[t - o] : 0u;
            __syncthreads();
            smem[t] = x + y;
            __syncthreads();
        }
        off[(size_t)k * NB1 + t] = smem[t] - v;
        if (t == 255) rowtot[k] = smem[t];
        __syncthreads();
    }
    gbar(bar);

    // ---- P3: add row prefixes (off becomes global offsets) ----
    for (int k = blockIdx.x; k < NBUCK; k += G) {
        unsigned s = 0;
        for (int j = t; j < k; j += 256) s += rowtot[j];
#pragma unroll
        for (int o = 1; o < 64; o <<= 1) s += __shfl_xor(s, o, 64);
        if ((t & 63) == 0) smem[256 + (t >> 6)] = s;
        __syncthreads();
        unsigned prefix = smem[256] + smem[257] + smem[258] + smem[259];
        off[(size_t)k * NB1 + t] += prefix;
        __syncthreads();
    }
    gbar(bar);

    // ---- P4: level-1 scatter -> bucket-major rec2 (ranks via LDS atomics) ----
    // rec = head(18b)<<45 | tail(18b)<<27 | rel(6b)<<21 | eid(21b)
    for (int vb = blockIdx.x; vb < NB1; vb += G) {
        unsigned* lh = smem;             // NBUCK
        unsigned* loff = smem + NBUCK;   // NBUCK
        for (int j = t; j < NBUCK; j += 256) {
            lh[j] = 0;
            loff[j] = off[(size_t)j * NB1 + vb];
        }
        __syncthreads();
        int base = vb * EPB;
        int end = base + EPB; if (end > N_EDGES) end = N_EDGES;
        for (int e = base + t; e < end; e += 256) {
            unsigned h = (unsigned)head[e];
            unsigned bkt = h >> 8;
            unsigned r = atomicAdd(&lh[bkt], 1u);
            u64 R = ((u64)h << 45) | ((u64)(unsigned)tailp[e] << 27)
                  | ((u64)(unsigned)(etype[e] - 1) << 21) | (u64)(unsigned)e;
            rec2[loff[bkt] + r] = R;
        }
        __syncthreads();
    }
    gbar(bar);

    // ---- P5: per-bucket CSR (two passes over rec2; ranks in LDS u16) ----
    for (int bkt = blockIdx.x; bkt < NBUCK; bkt += G) {
        unsigned* lh = smem;                                  // 256
        unsigned* lscan = smem + 256;                         // 256
        unsigned short* srank = (unsigned short*)(smem + 512);// L2CAP u16
        const unsigned gstart = off[(size_t)bkt * NB1];
        const unsigned gend = (bkt == NBUCK - 1) ? (unsigned)N_EDGES
                                                 : off[(size_t)(bkt + 1) * NB1];
        unsigned n = gend - gstart;
        if (n > L2CAP) n = L2CAP;   // statistically impossible; guards LDS
        lh[t] = 0;
        __syncthreads();
        for (unsigned j = t; j < n; j += 256) {
            u64 R = rec2[gstart + j];
            unsigned hl = (unsigned)(R >> 45) & 255u;
            srank[j] = (unsigned short)atomicAdd(&lh[hl], 1u);
        }
        __syncthreads();
        unsigned v = lh[t];
        lscan[t] = v;
        __syncthreads();
        for (int o = 1; o < 256; o <<= 1) {
            unsigned x = lscan[t];
            unsigned y = (t >= o) ? lscan[t - o] : 0u;
            __syncthreads();
            lscan[t] = x + y;
            __syncthreads();
        }
        unsigned excl = lscan[t] - v;
        __syncthreads();
        lscan[t] = excl;
        const int h0 = bkt * 256;
        const int entCount = (N_ENTITIES - h0 < 256) ? (N_ENTITIES - h0) : 256;
        if (t < entCount) {
            start[h0 + t] = gstart + excl;
            degtot[h0 + t] = v;
        }
        __syncthreads();
        for (unsigned j = t; j < n; j += 256) {   // re-read (L2-hot), write permuted
            u64 R = rec2[gstart + j];
            unsigned hl = (unsigned)(R >> 45) & 255u;
            rec3[gstart + lscan[hl] + srank[j]] = R;
        }
        __syncthreads();
    }
    gbar(bar);

    // ---- P6: node_pass (grid-stride, one wave per node per step) ----
    {
        const int wid = (blockIdx.x * 256 + t) >> 6;
        const int W = G * 4;
        const int lane = t & 63;
        const int slot = lane >> 4, sl = lane & 15;
        for (int node = wid; node < N_ENTITIES; node += W) {
            unsigned s = start[node], len = degtot[node];
            float4 ph = proj4[(size_t)node * 16 + sl];
            float dsum = 0.f, lsum = 0.f;
            for (unsigned k0 = 0; k0 < len; k0 += 8) {
                unsigned ka = k0 + slot, kb = ka + 4;
                bool va = (ka < len), vb = (kb < len);
                u64 Ra = rec3[s + (va ? ka : 0u)];
                u64 Rb = rec3[s + (vb ? kb : 0u)];
                unsigned ta = (unsigned)(Ra >> 27) & 0x3FFFFu, ria = ((unsigned)(Ra >> 21)) & 63u;
                unsigned tb = (unsigned)(Rb >> 27) & 0x3FFFFu, rib = ((unsigned)(Rb >> 21)) & 63u;
                unsigned ea = (unsigned)Ra & 0x1FFFFFu, eb = (unsigned)Rb & 0x1FFFFFu;
                float4 pa = proj4[(size_t)ta * 16 + sl];
                float4 qa = rel4[(size_t)ria * 16 + sl];
                float4 pb = proj4[(size_t)tb * 16 + sl];
                float4 qb = rel4[(size_t)rib * 16 + sl];
                float xa = ph.x * pa.x * qa.x + ph.y * pa.y * qa.y
                         + ph.z * pa.z * qa.z + ph.w * pa.w * qa.w;
                float xb = ph.x * pb.x * qb.x + ph.y * pb.y * qb.y
                         + ph.z * pb.z * qb.z + ph.w * pb.w * qb.w;
                xa += __shfl_xor(xa, 1, 64);  xb += __shfl_xor(xb, 1, 64);
                xa += __shfl_xor(xa, 2, 64);  xb += __shfl_xor(xb, 2, 64);
                xa += __shfl_xor(xa, 4, 64);  xb += __shfl_xor(xb, 4, 64);
                xa += __shfl_xor(xa, 8, 64);  xb += __shfl_xor(xb, 8, 64);
                if (sl == 0) {
                    if (va) {
                        float lg = xa * SCALE;
                        logits[ea] = lg;
                        dsum += __expf(lg);
                        lsum += lg;
                        if (ta < N_ITEMS) atomicAdd(&sumI[ta], lg);   // non-returning: free
                    }
                    if (vb) {
                        float lg = xb * SCALE;
                        logits[eb] = lg;
                        dsum += __expf(lg);
                        lsum += lg;
                        if (tb < N_ITEMS) atomicAdd(&sumI[tb], lg);
                    }
                }
            }
            dsum += __shfl_xor(dsum, 16, 64);
            dsum += __shfl_xor(dsum, 32, 64);
            lsum += __shfl_xor(lsum, 16, 64);
            lsum += __shfl_xor(lsum, 32, 64);
            if (lane == 0) {
                nd[node] = make_float2(dsum, (float)len);
                sumhead[node] = lsum;
            }
        }
    }
    gbar(bar);

    // ---- P7: scores + gumbel keys + item keys; LDS hist, one atomic flush ----
    {
        unsigned* hh = smem;   // 512
        for (int j = t; j < 512; j += 256) hh[j] = 0;
        __syncthreads();
        const int stride = G * 256;
        for (int i = blockIdx.x * 256 + t; i < N_EDGES; i += stride) {
            float lg = logits[i];
            float2 dd = nd[head[i]];
            float score = __expf(lg) / dd.x * dd.y;
            out_scores[i] = score;
            float noise = -logf(-logf(noise_u[i]));   // library logf: accurate near u->1
            unsigned k = fkey(score + noise);
            keysE[i] = k;
            atomicAdd(&hh[k >> 24], 1u);
            if (i < N_ITEMS) {
                unsigned ki = fkey(sumhead[i] + sumI[i]);
                keysI[i] = ki;
                atomicAdd(&hh[256 + (ki >> 24)], 1u);
            }
        }
        __syncthreads();
        for (int j = t; j < 512; j += 256) {
            unsigned v = hh[j];
            if (v) atomicAdd(&hists[j], v);   // non-returning: free
        }
    }
    gbar(bar);

    // ---- P8: collect candidates >= 8-bit threshold (both lists) ----
    {
        const int stride = G * 256;
        unsigned aboveA;
        unsigned binA = select_digit(hists, K_EDGES, &aboveA);
        unsigned T = binA << 24;
        for (int i = blockIdx.x * 256 + t; i < N_EDGES; i += stride) {
            unsigned k = keysE[i];
            if (k >= T) {
                unsigned p = atomicAdd(&counters[0], 1u);   // rare (~1.4k)
                if (p < (unsigned)CAND_CAP) { cand[2 * p] = k; cand[2 * p + 1] = (unsigned)i; }
            }
        }
        binA = select_digit(hists + 256, K_ITEMS, &aboveA);
        T = binA << 24;
        unsigned* cd = cand + 2 * CAND_CAP;
        for (int i = blockIdx.x * 256 + t; i < N_ITEMS; i += stride) {
            unsigned k = keysI[i];
            if (k >= T) {
                unsigned p = atomicAdd(&counters[1], 1u);   // rare (~200)
                if (p < (unsigned)CAND_CAP) { cd[2 * p] = k; cd[2 * p + 1] = (unsigned)i; }
            }
        }
    }
    gbar(bar);

    // ---- P9: exact rank among candidates (blocks 0..15; cand is L2-hot) ----
    if (blockIdx.x < 16) {
        const int y = blockIdx.x >> 3;
        const int sub = blockIdx.x & 7;
        const int K = y ? K_ITEMS : K_EDGES;
        float* outv = y ? out_itemv : out_topkv;
        float* outi = y ? out_itemi : out_topki;
        const unsigned* cd = cand + (size_t)y * 2 * CAND_CAP;
        unsigned m = counters[y];
        if (m > (unsigned)CAND_CAP) m = CAND_CAP;
        for (unsigned i = sub * 256 + t; i < m; i += 2048) {
            unsigned ki = cd[2 * i], xi = cd[2 * i + 1];
            int r = 0;
            for (unsigned j = 0; j < m; ++j) {
                unsigned kj = cd[2 * j];
                if (kj > ki || (kj == ki && cd[2 * j + 1] < xi)) r++;
            }
            if (r < K) {
                outv[r] = funkey(ki);
                outi[r] = (float)xi;
            }
        }
    }
}

extern "C" void kernel_launch(void* const* d_in, const int* in_sizes, int n_in,
                              void* d_out, int out_size, void* d_ws, size_t ws_size,
                              hipStream_t stream) {
    (void)in_sizes; (void)n_in; (void)out_size; (void)ws_size;
    const float* emb    = (const float*)d_in[0];
    const float* W      = (const float*)d_in[1];
    const float* rel    = (const float*)d_in[2];
    const float* noise  = (const float*)d_in[3];
    const int*   eidx   = (const int*)d_in[4];
    const int*   etype  = (const int*)d_in[5];
    const int* head = eidx;
    const int* tail = eidx + N_EDGES;

    float* out        = (float*)d_out;
    float* out_scores = out;
    float* out_topkv  = out + N_EDGES;
    float* out_topki  = out + N_EDGES + K_EDGES;
    float* out_itemv  = out + N_EDGES + 2 * K_EDGES;
    float* out_itemi  = out + N_EDGES + 2 * K_EDGES + K_ITEMS;

    float* ws = (float*)d_ws;
    size_t o = 0;
    float*    proj    = ws + o;               o += (size_t)N_ENTITIES * DIM;
    unsigned* off     = (unsigned*)(ws + o);  o += NSC;
    unsigned* rowtot  = (unsigned*)(ws + o);  o += 1024;
    u64*      rec2    = (u64*)(ws + o);       o += 2 * (size_t)N_EDGES;   // bucket-major
    u64*      rec3    = (u64*)(ws + o);       o += 2 * (size_t)N_EDGES;   // CSR-ordered
    unsigned* keysE   = (unsigned*)rec2;      // rec2 dead after P5
    unsigned* keysI   = keysE + N_EDGES;
    unsigned* start   = (unsigned*)(ws + o);  o += N_ENTITIES;
    unsigned* degtot  = (unsigned*)(ws + o);  o += N_ENTITIES;
    float*    logits  = ws + o;               o += N_EDGES;
    float2*   nd      = (float2*)(ws + o);    o += 2 * (size_t)N_ENTITIES;
    float*    sumhead = ws + o;               o += N_ENTITIES;
    float*    sumI    = ws + o;               o += N_ITEMS;      // memset begins
    unsigned* hists   = (unsigned*)(ws + o);  o += 512;
    unsigned* counters= (unsigned*)(ws + o);  o += 2;
    unsigned* bar     = (unsigned*)(ws + o);  o += 16;           // memset ends
    unsigned* cand    = (unsigned*)(ws + o);  o += 2 * 2 * CAND_CAP;

    // grid = exact co-resident capacity for mega_kernel (occupancy query on
    // the real kernel handle accounts for its actual VGPR/LDS). Static: once.
    static int G = 0;
    if (G == 0) {
        int dev = 0;
        hipGetDevice(&dev);
        hipDeviceProp_t prop;
        int cus = 256;
        if (hipGetDeviceProperties(&prop, dev) == hipSuccess) cus = prop.multiProcessorCount;
        int occ = 0;
        if (hipOccupancyMaxActiveBlocksPerMultiprocessor(&occ, mega_kernel, 256, 0) != hipSuccess
            || occ < 1) occ = 1;
        G = occ * cus;
        if (G < 16) G = 16;
        if (G > 4096) G = 4096;
    }

    // zero: sumI + hists + counters + bar (contiguous, ~0.4MB)
    hipMemsetAsync(sumI, 0, ((size_t)N_ITEMS + 512 + 2 + 16) * 4, stream);
    // pure GEMM (separate: keeps its register pressure out of the mega-kernel)
    hipLaunchKernelGGL(proj_kernel, dim3(12500), dim3(256), 0, stream, emb, W, proj);
    // everything else: one persistent kernel, 8 grid barriers
    hipLaunchKernelGGL(mega_kernel, dim3(G), dim3(256), 0, stream,
                       head, tail, etype,
                       (const float4*)proj, (const float4*)rel, noise,
                       off, rowtot, rec2, rec3, start, degtot,
                       logits, nd, sumhead, sumI,
                       out_scores, keysE, keysI, hists, counters, cand,
                       out_topkv, out_topki, out_itemv, out_itemi, bar);
}

// Round 11
// 437.208 us; speedup vs baseline: 3.3539x; 3.3539x over previous
//
#include <hip/hip_runtime.h>

#define N_ENTITIES 200000
#define N_ITEMS    100000
#define DIM        64
#define N_EDGES    1500000
#define K_EDGES    256
#define K_ITEMS    100
// 1 / (2 * sqrt(32))  (mean over 2 heads of per-head 1/sqrt(Dk))
#define SCALE      0.08838834764831845f

#define CAND_CAP   8192
#define NBLK3      1024      // edge_pass3 grid
#define NB1        256       // level-1 virtual blocks
#define EPB        5860      // edges per virtual block (256*5860 >= 1.5M)
#define BSH        6         // bucket shift: head>>6
#define NBUCK      3125      // 200000 >> 6
#define NSC        (NBUCK * NB1)   // 800000, exactly 3125*256
#define L2CAP      768       // max edges/bucket (Poisson mean 480, +13 sigma)

typedef unsigned long long u64;

// NOTE (round-0): fp16/bf16 storage of proj is FORBIDDEN (ordered top-100 item
// list; adjacent gaps ~8e-6; fp16 error 2.7e-6 -> rank flips). f32 only.
// NOTE (rounds 3-8, atomic saga): gfx950 global atomics execute memory-side
// regardless of scope/sc-bits. NON-RETURNING atomics are FREE (r7). RETURNING
// global atomics drain ~50ns each (1.5M = ~75us). Ranks belong in LDS atomics.
// NOTE (r8/r9): node-major CSR is the right shape: 293MB @ ~3.0TB/s random-
// gather ceiling = 99us node_pass floor. Edge-centric = 467MB = 160us.
// NOTE (r10): persistent mega-kernel with agent-scope spin barriers = 3.4x
// REGRESSION (1466us). Spin-polls hammer the memory-side coherence point.
// NEVER replace stream ordering with global software barriers on gfx950.
// This round: fusion along BLOCK-LOCAL dependencies only (bucket -> its own
// nodes), which needs no global sync at all.

// ---- monotonic float<->u32 key (order-preserving, total order) ----
__device__ __forceinline__ unsigned fkey(float x) {
    unsigned u = __float_as_uint(x);
    return (u & 0x80000000u) ? ~u : (u | 0x80000000u);
}
__device__ __forceinline__ float funkey(unsigned k) {
    return (k & 0x80000000u) ? __uint_as_float(k & 0x7fffffffu)
                             : __uint_as_float(~k);
}

// serial 256-bin select: largest bin b with count(>b) < Keff <= count(>=b).
__device__ __forceinline__ unsigned select_digit(const unsigned* __restrict__ hist,
                                                 unsigned Keff, unsigned* above) {
    unsigned cum = 0;
    int b = 255;
    for (; b > 0; --b) {
        unsigned hb = hist[b];
        if (cum + hb >= Keff) break;
        cum += hb;
    }
    *above = cum;
    return (unsigned)b;
}

// ---- proj = emb @ W_Q. Pure GEMM, no atomics. ----
__global__ __launch_bounds__(256) void proj_kernel(const float* __restrict__ emb,
                                                   const float* __restrict__ W,
                                                   float* __restrict__ proj) {
    __shared__ float part[4][16][64];
    const int t = threadIdx.x;
    const int c = t & 63;
    const int q = __builtin_amdgcn_readfirstlane(t >> 6);

    float Wreg[16];
#pragma unroll
    for (int j = 0; j < 16; ++j) Wreg[j] = W[(q * 16 + j) * 64 + c];

    const int base = blockIdx.x * 16;   // 200000 = 12500 * 16, exact
    const float* erow = emb + (size_t)base * 64 + q * 16;

    float acc[16];
#pragma unroll
    for (int r = 0; r < 16; ++r) acc[r] = 0.f;
#pragma unroll
    for (int r = 0; r < 16; ++r) {
#pragma unroll
        for (int j = 0; j < 16; ++j)
            acc[r] += erow[r * 64 + j] * Wreg[j];
    }
#pragma unroll
    for (int r = 0; r < 16; ++r) part[q][r][c] = acc[r];
    __syncthreads();
#pragma unroll
    for (int it = 0; it < 4; ++it) {
        int oi = t + it * 256;
        int r = oi >> 6, cc = oi & 63;
        float s = part[0][r][cc] + part[1][r][cc] + part[2][r][cc] + part[3][r][cc];
        proj[(size_t)(base + r) * 64 + cc] = s;
    }
}

// ---- level-1 bucket histogram: per-virtual-block counts of head>>BSH ----
__global__ __launch_bounds__(256) void bhist_kernel(const int* __restrict__ head,
                                                    unsigned* __restrict__ off) {
    __shared__ unsigned lh[NBUCK];
    for (int k = threadIdx.x; k < NBUCK; k += 256) lh[k] = 0;
    __syncthreads();
    int base = blockIdx.x * EPB;
    int end = base + EPB; if (end > N_EDGES) end = N_EDGES;
    for (int e = base + threadIdx.x; e < end; e += 256)
        atomicAdd(&lh[(unsigned)head[e] >> BSH], 1u);   // LDS atomic: cheap
    __syncthreads();
    for (int k = threadIdx.x; k < NBUCK; k += 256)
        off[(size_t)k * NB1 + blockIdx.x] = lh[k];
}

// ---- hierarchical exclusive scan over NSC elements (in place) ----
__global__ void scanA_kernel(unsigned* __restrict__ a, unsigned* __restrict__ bsum) {
    __shared__ unsigned s[256];
    int t = threadIdx.x, i = blockIdx.x * 256 + t;
    unsigned v = a[i];                  // NSC exactly divisible, no bounds check
    s[t] = v;
    __syncthreads();
    for (int off = 1; off < 256; off <<= 1) {
        unsigned x = s[t];
        unsigned y = (t >= off) ? s[t - off] : 0u;
        __syncthreads();
        s[t] = x + y;
        __syncthreads();
    }
    a[i] = s[t] - v;                    // block-local exclusive
    if (t == 255) bsum[blockIdx.x] = s[t];
}
__global__ __launch_bounds__(256) void scanB_kernel(const unsigned* __restrict__ bsum,
                                                    unsigned* __restrict__ a) {
    __shared__ unsigned part[4];
    const int b = blockIdx.x;
    const int t = threadIdx.x;
    unsigned s = 0;
    for (int j = t; j < b; j += 256) s += bsum[j];
#pragma unroll
    for (int off = 1; off < 64; off <<= 1) s += __shfl_xor(s, off, 64);
    if ((t & 63) == 0) part[t >> 6] = s;
    __syncthreads();
    unsigned prefix = part[0] + part[1] + part[2] + part[3];
    a[b * 256 + t] += prefix;
}

// ---- level-1 scatter: edges -> bucket-major rec2 (ranks via LDS atomics) ----
// rec = head(18b)<<45 | tail(18b)<<27 | rel(6b)<<21 | eid(21b)
__global__ __launch_bounds__(256) void bscat_kernel(const int* __restrict__ head,
                                                    const int* __restrict__ tail,
                                                    const int* __restrict__ etype,
                                                    const unsigned* __restrict__ off,
                                                    u64* __restrict__ rec2) {
    __shared__ unsigned lh[NBUCK];
    __shared__ unsigned loff[NBUCK];
    for (int k = threadIdx.x; k < NBUCK; k += 256) {
        lh[k] = 0;
        loff[k] = off[(size_t)k * NB1 + blockIdx.x];
    }
    __syncthreads();
    int base = blockIdx.x * EPB;
    int end = base + EPB; if (end > N_EDGES) end = N_EDGES;
    for (int e = base + threadIdx.x; e < end; e += 256) {
        unsigned h = (unsigned)head[e];
        unsigned bkt = h >> BSH;
        unsigned r = atomicAdd(&lh[bkt], 1u);          // LDS returning atomic: cheap
        u64 R = ((u64)h << 45) | ((u64)(unsigned)tail[e] << 27)
              | ((u64)(unsigned)(etype[e] - 1) << 21) | (u64)(unsigned)e;
        rec2[loff[bkt] + r] = R;
    }
}

// ---- FUSED per-bucket CSR + node pass. Bucket -> its 64 nodes is a
// block-local dependency: build the CSR in LDS, then process the nodes
// directly from LDS records. rec3/start/degtot never touch global memory.
__global__ __launch_bounds__(256) void csrnode_kernel(const u64* __restrict__ rec2,
                                                      const unsigned* __restrict__ off,
                                                      const float4* __restrict__ proj4,
                                                      const float4* __restrict__ rel4,
                                                      float* __restrict__ logits,
                                                      float2* __restrict__ nd,
                                                      float* __restrict__ sumhead,
                                                      float* __restrict__ sumI) {
    __shared__ u64 sdst[L2CAP];
    __shared__ unsigned short srank[L2CAP];
    __shared__ unsigned lh[64];
    __shared__ unsigned lscan[64];
    const int t = threadIdx.x;
    const int bkt = blockIdx.x;
    const unsigned gstart = off[(size_t)bkt * NB1];
    const unsigned gend = (bkt == NBUCK - 1) ? (unsigned)N_EDGES
                                             : off[(size_t)(bkt + 1) * NB1];
    unsigned n = gend - gstart;
    if (n > L2CAP) n = L2CAP;   // statistically impossible (+13 sigma); LDS guard
    if (t < 64) lh[t] = 0;
    __syncthreads();
    // pass 1: per-entity ranks (LDS atomics; rec2 read is L2-warm)
    for (unsigned j = t; j < n; j += 256) {
        u64 R = rec2[gstart + j];
        unsigned hl = (unsigned)(R >> 45) & 63u;
        srank[j] = (unsigned short)atomicAdd(&lh[hl], 1u);
    }
    __syncthreads();
    // exclusive scan of 64 per-entity counts
    unsigned v0 = (t < 64) ? lh[t] : 0u;
    if (t < 64) lscan[t] = v0;
    __syncthreads();
    for (int o = 1; o < 64; o <<= 1) {
        unsigned x = 0, y = 0;
        if (t < 64) { x = lscan[t]; y = (t >= o) ? lscan[t - o] : 0u; }
        __syncthreads();
        if (t < 64) lscan[t] = x + y;
        __syncthreads();
    }
    if (t < 64) lscan[t] -= v0;   // exclusive
    __syncthreads();
    // pass 2: permute records into CSR order within LDS
    for (unsigned j = t; j < n; j += 256) {
        u64 R = rec2[gstart + j];
        unsigned hl = (unsigned)(R >> 45) & 63u;
        sdst[lscan[hl] + srank[j]] = R;
    }
    __syncthreads();

    // node phase: wave wv handles nodes wv*16..wv*16+15 (one node at a time,
    // identical per-node math/order structure to r9's node_pass).
    const int lane = t & 63;
    const int wv = t >> 6;
    const int slot = lane >> 4, sl = lane & 15;
    for (int ln = 0; ln < 16; ++ln) {
        const int local = wv * 16 + ln;
        const int node = (bkt << 6) + local;
        const unsigned s0 = lscan[local];
        const unsigned len = lh[local];
        float4 ph = proj4[(size_t)node * 16 + sl];
        float dsum = 0.f, lsum = 0.f;
        for (unsigned k0 = 0; k0 < len; k0 += 8) {
            unsigned ka = k0 + slot, kb = ka + 4;
            bool va = (ka < len), vb = (kb < len);
            u64 Ra = sdst[s0 + (va ? ka : 0u)];
            u64 Rb = sdst[s0 + (vb ? kb : 0u)];
            unsigned ta = (unsigned)(Ra >> 27) & 0x3FFFFu, ria = ((unsigned)(Ra >> 21)) & 63u;
            unsigned tb = (unsigned)(Rb >> 27) & 0x3FFFFu, rib = ((unsigned)(Rb >> 21)) & 63u;
            unsigned ea = (unsigned)Ra & 0x1FFFFFu, eb = (unsigned)Rb & 0x1FFFFFu;
            float4 pa = proj4[(size_t)ta * 16 + sl];
            float4 qa = rel4[(size_t)ria * 16 + sl];
            float4 pb = proj4[(size_t)tb * 16 + sl];
            float4 qb = rel4[(size_t)rib * 16 + sl];
            float xa = ph.x * pa.x * qa.x + ph.y * pa.y * qa.y
                     + ph.z * pa.z * qa.z + ph.w * pa.w * qa.w;
            float xb = ph.x * pb.x * qb.x + ph.y * pb.y * qb.y
                     + ph.z * pb.z * qb.z + ph.w * pb.w * qb.w;
            xa += __shfl_xor(xa, 1, 64);  xb += __shfl_xor(xb, 1, 64);
            xa += __shfl_xor(xa, 2, 64);  xb += __shfl_xor(xb, 2, 64);
            xa += __shfl_xor(xa, 4, 64);  xb += __shfl_xor(xb, 4, 64);
            xa += __shfl_xor(xa, 8, 64);  xb += __shfl_xor(xb, 8, 64);
            if (sl == 0) {
                if (va) {
                    float lg = xa * SCALE;
                    logits[ea] = lg;
                    dsum += __expf(lg);
                    lsum += lg;
                    if (ta < N_ITEMS) atomicAdd(&sumI[ta], lg);   // non-returning: free
                }
                if (vb) {
                    float lg = xb * SCALE;
                    logits[eb] = lg;
                    dsum += __expf(lg);
                    lsum += lg;
                    if (tb < N_ITEMS) atomicAdd(&sumI[tb], lg);
                }
            }
        }
        dsum += __shfl_xor(dsum, 16, 64);
        dsum += __shfl_xor(dsum, 32, 64);
        lsum += __shfl_xor(lsum, 16, 64);
        lsum += __shfl_xor(lsum, 32, 64);
        if (lane == 0) {
            nd[node] = make_float2(dsum, (float)len);
            sumhead[node] = lsum;
        }
    }
}

// ---- scores + gumbel keys + item keys; LDS hist, non-returning atomic flush ----
__global__ __launch_bounds__(256) void edge_pass3(const float* __restrict__ logits,
                           const int* __restrict__ head,
                           const float2* __restrict__ nd, const float* __restrict__ noise_u,
                           const float* __restrict__ sumhead, const float* __restrict__ sumI,
                           float* __restrict__ out_scores, unsigned* __restrict__ keysE,
                           unsigned* __restrict__ keysI, unsigned* __restrict__ hists) {
    __shared__ unsigned hh[512];   // [0..255]=edge bins, [256..511]=item bins
    for (int j = threadIdx.x; j < 512; j += blockDim.x) hh[j] = 0;
    __syncthreads();
    const int stride = NBLK3 * 256;
    for (int i = blockIdx.x * blockDim.x + threadIdx.x; i < N_EDGES; i += stride) {
        float lg = logits[i];
        float2 dd = nd[head[i]];   // (denom, deg); 1.6MB -> cached
        float score = __expf(lg) / dd.x * dd.y;
        out_scores[i] = score;
        float noise = -logf(-logf(noise_u[i]));   // library logf: accurate near u->1
        unsigned k = fkey(score + noise);
        keysE[i] = k;
        atomicAdd(&hh[k >> 24], 1u);
        if (i < N_ITEMS) {
            unsigned ki = fkey(sumhead[i] + sumI[i]);
            keysI[i] = ki;
            atomicAdd(&hh[256 + (ki >> 24)], 1u);
        }
    }
    __syncthreads();
    for (int j = threadIdx.x; j < 512; j += blockDim.x) {
        unsigned v = hh[j];
        if (v) atomicAdd(&hists[j], v);   // non-returning global atomic: free (r7)
    }
}

// ---- collect candidates >= 8-bit (sign+exponent) threshold ----
__global__ void collect_kernel(const unsigned* __restrict__ keysE,
                               const unsigned* __restrict__ keysI,
                               const unsigned* __restrict__ hists,
                               unsigned* __restrict__ counters, unsigned* __restrict__ cand) {
    const int y = blockIdx.y;
    const unsigned* keys = y ? keysI : keysE;
    const int n = y ? N_ITEMS : N_EDGES;
    const unsigned K = y ? K_ITEMS : K_EDGES;
    const unsigned* H = hists + (size_t)y * 256;
    unsigned aboveA;
    unsigned binA = select_digit(H, K, &aboveA);
    const unsigned T = binA << 24;
    unsigned* cd = cand + (size_t)y * 2 * CAND_CAP;

    int i = blockIdx.x * blockDim.x + threadIdx.x;
    int stride = gridDim.x * blockDim.x;
    for (; i < n; i += stride) {
        unsigned k = keys[i];
        if (k >= T) {
            unsigned p = atomicAdd(&counters[y], 1u);   // rare (~1.6k total): fine
            if (p < (unsigned)CAND_CAP) { cd[2 * p] = k; cd[2 * p + 1] = (unsigned)i; }
        }
    }
}

// ---- exact rank among candidates (key desc, index asc); 2 blocks (y) ----
__global__ void final_topk_kernel(const unsigned* __restrict__ cand,
                                  const unsigned* __restrict__ counters,
                                  float* __restrict__ out_topkv, float* __restrict__ out_topki,
                                  float* __restrict__ out_itemv, float* __restrict__ out_itemi) {
    __shared__ unsigned sk[CAND_CAP];
    __shared__ unsigned si[CAND_CAP];
    const int y = blockIdx.x;
    const int K = y ? K_ITEMS : K_EDGES;
    float* outv = y ? out_itemv : out_topkv;
    float* outi = y ? out_itemi : out_topki;
    const unsigned* cd = cand + (size_t)y * 2 * CAND_CAP;
    unsigned m = counters[y];
    if (m > (unsigned)CAND_CAP) m = CAND_CAP;
    for (unsigned i = threadIdx.x; i < m; i += blockDim.x) {
        sk[i] = cd[2 * i];
        si[i] = cd[2 * i + 1];
    }
    __syncthreads();
    for (unsigned i = threadIdx.x; i < m; i += blockDim.x) {
        unsigned ki = sk[i], xi = si[i];
        int r = 0;
        for (unsigned j = 0; j < m; ++j) {
            unsigned kj = sk[j];
            if (kj > ki || (kj == ki && si[j] < xi)) r++;
        }
        if (r < K) {
            outv[r] = funkey(ki);
            outi[r] = (float)xi;
        }
    }
}

extern "C" void kernel_launch(void* const* d_in, const int* in_sizes, int n_in,
                              void* d_out, int out_size, void* d_ws, size_t ws_size,
                              hipStream_t stream) {
    (void)in_sizes; (void)n_in; (void)out_size; (void)ws_size;
    const float* emb    = (const float*)d_in[0];
    const float* W      = (const float*)d_in[1];
    const float* rel    = (const float*)d_in[2];
    const float* noise  = (const float*)d_in[3];
    const int*   eidx   = (const int*)d_in[4];
    const int*   etype  = (const int*)d_in[5];
    const int* head = eidx;
    const int* tail = eidx + N_EDGES;

    float* out        = (float*)d_out;
    float* out_scores = out;
    float* out_topkv  = out + N_EDGES;
    float* out_topki  = out + N_EDGES + K_EDGES;
    float* out_itemv  = out + N_EDGES + 2 * K_EDGES;
    float* out_itemi  = out + N_EDGES + 2 * K_EDGES + K_ITEMS;

    float* ws = (float*)d_ws;
    size_t o = 0;
    float*    proj    = ws + o;               o += (size_t)N_ENTITIES * DIM;
    unsigned* off     = (unsigned*)(ws + o);  o += NSC;
    unsigned* bsum    = (unsigned*)(ws + o);  o += 3200;
    u64*      rec2    = (u64*)(ws + o);       o += 2 * (size_t)N_EDGES;   // bucket-major
    unsigned* keysE   = (unsigned*)rec2;      // rec2 dead after csrnode
    unsigned* keysI   = keysE + N_EDGES;
    float*    logits  = ws + o;               o += N_EDGES;
    float2*   nd      = (float2*)(ws + o);    o += 2 * (size_t)N_ENTITIES;
    float*    sumhead = ws + o;               o += N_ENTITIES;
    float*    sumI    = ws + o;               o += N_ITEMS;      // memset begins
    unsigned* hists   = (unsigned*)(ws + o);  o += 512;
    unsigned* counters= (unsigned*)(ws + o);  o += 2;            // memset ends
    unsigned* cand    = (unsigned*)(ws + o);  o += 2 * 2 * CAND_CAP;

    // zero: sumI + hists + counters (contiguous, ~0.4MB)
    hipMemsetAsync(sumI, 0, ((size_t)N_ITEMS + 512 + 2) * 4, stream);
    // pure GEMM
    hipLaunchKernelGGL(proj_kernel, dim3(12500), dim3(256), 0, stream, emb, W, proj);
    // atomic-free CSR build (level 1): hist -> scan -> scatter to bucket-major
    hipLaunchKernelGGL(bhist_kernel, dim3(NB1), dim3(256), 0, stream, head, off);
    hipLaunchKernelGGL(scanA_kernel, dim3(NSC / 256), dim3(256), 0, stream, off, bsum);
    hipLaunchKernelGGL(scanB_kernel, dim3(NSC / 256), dim3(256), 0, stream, bsum, off);
    hipLaunchKernelGGL(bscat_kernel, dim3(NB1), dim3(256), 0, stream,
                       head, tail, etype, off, rec2);
    // FUSED level-2 CSR + node pass (block-local dependency; no rec3/start/degtot)
    hipLaunchKernelGGL(csrnode_kernel, dim3(NBUCK), dim3(256), 0, stream,
                       rec2, off, (const float4*)proj, (const float4*)rel,
                       logits, nd, sumhead, sumI);
    // scores + noisy keys + item keys + hist (LDS + free atomic flush)
    hipLaunchKernelGGL(edge_pass3, dim3(NBLK3), dim3(256), 0, stream,
                       logits, head, nd, noise, sumhead, sumI,
                       out_scores, keysE, keysI, hists);
    // top-k: single 8-bit threshold collect + exact rank
    hipLaunchKernelGGL(collect_kernel, dim3(512, 2), dim3(256), 0, stream,
                       keysE, keysI, hists, counters, cand);
    hipLaunchKernelGGL(final_topk_kernel, dim3(2), dim3(1024), 0, stream,
                       cand, counters, out_topkv, out_topki, out_itemv, out_itemi);
}

// Round 12
// 431.025 us; speedup vs baseline: 3.4020x; 1.0143x over previous
//
#include <hip/hip_runtime.h>

#define N_ENTITIES 200000
#define N_ITEMS    100000
#define DIM        64
#define N_EDGES    1500000
#define K_EDGES    256
#define K_ITEMS    100
// 1 / (2 * sqrt(32))  (mean over 2 heads of per-head 1/sqrt(Dk))
#define SCALE      0.08838834764831845f

#define CAND_CAP   8192
#define NBLK3      1024      // edge_pass3 grid
#define NB1        256       // level-1 virtual blocks
#define EPB        5860      // edges per virtual block (256*5860 >= 1.5M)
#define BSH        8         // bucket shift: head>>8 (256 entities/bucket)
#define NBUCK      782       // ceil(200000/256)
#define NSC        (NBUCK * NB1)   // 200192, exactly 782*256
#define L2CAP      2816      // max edges/bucket (mean 1918 + 20 sigma; r9-proven)
#define PROJB      12500     // proj GEMM blocks (200000/16)

typedef unsigned long long u64;

// NOTE (round-0): fp16/bf16 storage of proj is FORBIDDEN (ordered top-100 item
// list; adjacent gaps ~8e-6; fp16 error 2.7e-6 -> rank flips). f32 only.
// NOTE (rounds 3-8, atomic saga): gfx950 global atomics execute memory-side
// regardless of scope/sc-bits. NON-RETURNING atomics are FREE (r7). RETURNING
// global atomics drain ~50ns each (1.5M = ~75us). Ranks belong in LDS atomics.
// NOTE (r8/r9): node-major CSR is the right shape (293MB @ ~3TB/s random-
// gather ceiling); edge-centric = 467MB = 160us.
// NOTE (r10): persistent kernel + agent-scope spin barriers = 3.4x REGRESSION.
// Never replace stream ordering with global software barriers on gfx950.
// NOTE (r11): bucket granularity is a TRADE: fine buckets (3125) shrink
// csrnode LDS but make bscat writes sparse (~2 edges/bucket/vblock -> full
// write-allocate churn, 25KB LDS occupancy cap). 782 buckets = denser 60B
// write runs + 6KB LDS. This round: 782 buckets + csrnode fusion + proj/bhist
// grid-split fusion (independent work, one dispatch fewer).

// ---- monotonic float<->u32 key (order-preserving, total order) ----
__device__ __forceinline__ unsigned fkey(float x) {
    unsigned u = __float_as_uint(x);
    return (u & 0x80000000u) ? ~u : (u | 0x80000000u);
}
__device__ __forceinline__ float funkey(unsigned k) {
    return (k & 0x80000000u) ? __uint_as_float(k & 0x7fffffffu)
                             : __uint_as_float(~k);
}

// serial 256-bin select: largest bin b with count(>b) < Keff <= count(>=b).
__device__ __forceinline__ unsigned select_digit(const unsigned* __restrict__ hist,
                                                 unsigned Keff, unsigned* above) {
    unsigned cum = 0;
    int b = 255;
    for (; b > 0; --b) {
        unsigned hb = hist[b];
        if (cum + hb >= Keff) break;
        cum += hb;
    }
    *above = cum;
    return (unsigned)b;
}

// ---- fused proj GEMM + level-1 bucket histogram (independent work,
// grid-split: blocks < PROJB do GEMM, the rest do the histogram). ----
__global__ __launch_bounds__(256) void proj_bhist_kernel(const float* __restrict__ emb,
                                                         const float* __restrict__ W,
                                                         float* __restrict__ proj,
                                                         const int* __restrict__ head,
                                                         unsigned* __restrict__ off) {
    __shared__ float part[4][16][64];   // 16KB; aliased by the bhist branch
    const int t = threadIdx.x;

    if (blockIdx.x >= PROJB) {
        // ---- bhist branch (256 blocks) ----
        unsigned* lh = (unsigned*)&part[0][0][0];   // NBUCK=782 -> 3.1KB
        const int vb = blockIdx.x - PROJB;
        for (int k = t; k < NBUCK; k += 256) lh[k] = 0;
        __syncthreads();
        int base = vb * EPB;
        int end = base + EPB; if (end > N_EDGES) end = N_EDGES;
        for (int e = base + t; e < end; e += 256)
            atomicAdd(&lh[(unsigned)head[e] >> BSH], 1u);   // LDS atomic: cheap
        __syncthreads();
        for (int k = t; k < NBUCK; k += 256)
            off[(size_t)k * NB1 + vb] = lh[k];
        return;
    }

    // ---- GEMM branch ----
    const int c = t & 63;
    const int q = __builtin_amdgcn_readfirstlane(t >> 6);

    float Wreg[16];
#pragma unroll
    for (int j = 0; j < 16; ++j) Wreg[j] = W[(q * 16 + j) * 64 + c];

    const int base = blockIdx.x * 16;   // 200000 = 12500 * 16, exact
    const float* erow = emb + (size_t)base * 64 + q * 16;

    float acc[16];
#pragma unroll
    for (int r = 0; r < 16; ++r) acc[r] = 0.f;
#pragma unroll
    for (int r = 0; r < 16; ++r) {
#pragma unroll
        for (int j = 0; j < 16; ++j)
            acc[r] += erow[r * 64 + j] * Wreg[j];
    }
#pragma unroll
    for (int r = 0; r < 16; ++r) part[q][r][c] = acc[r];
    __syncthreads();
#pragma unroll
    for (int it = 0; it < 4; ++it) {
        int oi = t + it * 256;
        int r = oi >> 6, cc = oi & 63;
        float s = part[0][r][cc] + part[1][r][cc] + part[2][r][cc] + part[3][r][cc];
        proj[(size_t)(base + r) * 64 + cc] = s;
    }
}

// ---- hierarchical exclusive scan over NSC elements (in place) ----
__global__ void scanA_kernel(unsigned* __restrict__ a, unsigned* __restrict__ bsum) {
    __shared__ unsigned s[256];
    int t = threadIdx.x, i = blockIdx.x * 256 + t;
    unsigned v = a[i];                  // NSC exactly divisible, no bounds check
    s[t] = v;
    __syncthreads();
    for (int off = 1; off < 256; off <<= 1) {
        unsigned x = s[t];
        unsigned y = (t >= off) ? s[t - off] : 0u;
        __syncthreads();
        s[t] = x + y;
        __syncthreads();
    }
    a[i] = s[t] - v;                    // block-local exclusive
    if (t == 255) bsum[blockIdx.x] = s[t];
}
__global__ __launch_bounds__(256) void scanB_kernel(const unsigned* __restrict__ bsum,
                                                    unsigned* __restrict__ a) {
    __shared__ unsigned part[4];
    const int b = blockIdx.x;
    const int t = threadIdx.x;
    unsigned s = 0;
    for (int j = t; j < b; j += 256) s += bsum[j];
#pragma unroll
    for (int off = 1; off < 64; off <<= 1) s += __shfl_xor(s, off, 64);
    if ((t & 63) == 0) part[t >> 6] = s;
    __syncthreads();
    unsigned prefix = part[0] + part[1] + part[2] + part[3];
    a[b * 256 + t] += prefix;
}

// ---- level-1 scatter: edges -> bucket-major rec2 (ranks via LDS atomics) ----
// rec = head(18b)<<45 | tail(18b)<<27 | rel(6b)<<21 | eid(21b)
// 782 buckets: ~7.5 edges/bucket/vblock -> ~60B write runs (dense; r11 lesson)
__global__ __launch_bounds__(256) void bscat_kernel(const int* __restrict__ head,
                                                    const int* __restrict__ tail,
                                                    const int* __restrict__ etype,
                                                    const unsigned* __restrict__ off,
                                                    u64* __restrict__ rec2) {
    __shared__ unsigned lh[NBUCK];
    __shared__ unsigned loff[NBUCK];
    for (int k = threadIdx.x; k < NBUCK; k += 256) {
        lh[k] = 0;
        loff[k] = off[(size_t)k * NB1 + blockIdx.x];
    }
    __syncthreads();
    int base = blockIdx.x * EPB;
    int end = base + EPB; if (end > N_EDGES) end = N_EDGES;
    for (int e = base + threadIdx.x; e < end; e += 256) {
        unsigned h = (unsigned)head[e];
        unsigned bkt = h >> BSH;
        unsigned r = atomicAdd(&lh[bkt], 1u);          // LDS returning atomic: cheap
        u64 R = ((u64)h << 45) | ((u64)(unsigned)tail[e] << 27)
              | ((u64)(unsigned)(etype[e] - 1) << 21) | (u64)(unsigned)e;
        rec2[loff[bkt] + r] = R;
    }
}

// ---- FUSED per-bucket CSR + node pass (782 blocks, 256 entities each).
// Build the bucket's CSR in LDS, then run the node pass straight from LDS.
__global__ __launch_bounds__(256) void csrnode_kernel(const u64* __restrict__ rec2,
                                                      const unsigned* __restrict__ off,
                                                      const float4* __restrict__ proj4,
                                                      const float4* __restrict__ rel4,
                                                      float* __restrict__ logits,
                                                      float2* __restrict__ nd,
                                                      float* __restrict__ sumhead,
                                                      float* __restrict__ sumI) {
    __shared__ u64 sdst[L2CAP];                // 22.5KB
    __shared__ unsigned short srank[L2CAP];    // 5.6KB
    __shared__ unsigned lh[256];
    __shared__ unsigned lscan[256];
    const int t = threadIdx.x;
    const int bkt = blockIdx.x;
    const unsigned gstart = off[(size_t)bkt * NB1];
    const unsigned gend = (bkt == NBUCK - 1) ? (unsigned)N_EDGES
                                             : off[(size_t)(bkt + 1) * NB1];
    unsigned n = gend - gstart;
    if (n > L2CAP) n = L2CAP;   // statistically impossible (+20 sigma); LDS guard
    lh[t] = 0;
    __syncthreads();
    // pass 1: per-entity ranks (LDS atomics)
    for (unsigned j = t; j < n; j += 256) {
        u64 R = rec2[gstart + j];
        unsigned hl = (unsigned)(R >> 45) & 255u;
        srank[j] = (unsigned short)atomicAdd(&lh[hl], 1u);
    }
    __syncthreads();
    // exclusive scan of 256 per-entity counts
    unsigned v0 = lh[t];
    lscan[t] = v0;
    __syncthreads();
    for (int o = 1; o < 256; o <<= 1) {
        unsigned x = lscan[t];
        unsigned y = (t >= o) ? lscan[t - o] : 0u;
        __syncthreads();
        lscan[t] = x + y;
        __syncthreads();
    }
    unsigned excl = lscan[t] - v0;
    __syncthreads();
    lscan[t] = excl;
    __syncthreads();
    // pass 2: permute records into CSR order within LDS (rec2 re-read is L2-hot)
    for (unsigned j = t; j < n; j += 256) {
        u64 R = rec2[gstart + j];
        unsigned hl = (unsigned)(R >> 45) & 255u;
        sdst[lscan[hl] + srank[j]] = R;
    }
    __syncthreads();

    // node phase: wave wv handles 64 consecutive nodes; math order identical
    // to r9's node_pass (bit-identical per-node sums).
    const int lane = t & 63;
    const int wv = t >> 6;
    const int slot = lane >> 4, sl = lane & 15;
    for (int ln = 0; ln < 64; ++ln) {
        const int local = wv * 64 + ln;
        const int node = (bkt << BSH) + local;
        if (node >= N_ENTITIES) break;   // partial last bucket (200192 > 200000)
        const unsigned s0 = lscan[local];
        const unsigned len = lh[local];
        float4 ph = proj4[(size_t)node * 16 + sl];
        float dsum = 0.f, lsum = 0.f;
        for (unsigned k0 = 0; k0 < len; k0 += 8) {
            unsigned ka = k0 + slot, kb = ka + 4;
            bool va = (ka < len), vb = (kb < len);
            u64 Ra = sdst[s0 + (va ? ka : 0u)];
            u64 Rb = sdst[s0 + (vb ? kb : 0u)];
            unsigned ta = (unsigned)(Ra >> 27) & 0x3FFFFu, ria = ((unsigned)(Ra >> 21)) & 63u;
            unsigned tb = (unsigned)(Rb >> 27) & 0x3FFFFu, rib = ((unsigned)(Rb >> 21)) & 63u;
            unsigned ea = (unsigned)Ra & 0x1FFFFFu, eb = (unsigned)Rb & 0x1FFFFFu;
            float4 pa = proj4[(size_t)ta * 16 + sl];
            float4 qa = rel4[(size_t)ria * 16 + sl];
            float4 pb = proj4[(size_t)tb * 16 + sl];
            float4 qb = rel4[(size_t)rib * 16 + sl];
            float xa = ph.x * pa.x * qa.x + ph.y * pa.y * qa.y
                     + ph.z * pa.z * qa.z + ph.w * pa.w * qa.w;
            float xb = ph.x * pb.x * qb.x + ph.y * pb.y * qb.y
                     + ph.z * pb.z * qb.z + ph.w * pb.w * qb.w;
            xa += __shfl_xor(xa, 1, 64);  xb += __shfl_xor(xb, 1, 64);
            xa += __shfl_xor(xa, 2, 64);  xb += __shfl_xor(xb, 2, 64);
            xa += __shfl_xor(xa, 4, 64);  xb += __shfl_xor(xb, 4, 64);
            xa += __shfl_xor(xa, 8, 64);  xb += __shfl_xor(xb, 8, 64);
            if (sl == 0) {
                if (va) {
                    float lg = xa * SCALE;
                    logits[ea] = lg;
                    dsum += __expf(lg);
                    lsum += lg;
                    if (ta < N_ITEMS) atomicAdd(&sumI[ta], lg);   // non-returning: free
                }
                if (vb) {
                    float lg = xb * SCALE;
                    logits[eb] = lg;
                    dsum += __expf(lg);
                    lsum += lg;
                    if (tb < N_ITEMS) atomicAdd(&sumI[tb], lg);
                }
            }
        }
        dsum += __shfl_xor(dsum, 16, 64);
        dsum += __shfl_xor(dsum, 32, 64);
        lsum += __shfl_xor(lsum, 16, 64);
        lsum += __shfl_xor(lsum, 32, 64);
        if (lane == 0) {
            nd[node] = make_float2(dsum, (float)len);
            sumhead[node] = lsum;
        }
    }
}

// ---- scores + gumbel keys + item keys; LDS hist, non-returning atomic flush ----
__global__ __launch_bounds__(256) void edge_pass3(const float* __restrict__ logits,
                           const int* __restrict__ head,
                           const float2* __restrict__ nd, const float* __restrict__ noise_u,
                           const float* __restrict__ sumhead, const float* __restrict__ sumI,
                           float* __restrict__ out_scores, unsigned* __restrict__ keysE,
                           unsigned* __restrict__ keysI, unsigned* __restrict__ hists) {
    __shared__ unsigned hh[512];   // [0..255]=edge bins, [256..511]=item bins
    for (int j = threadIdx.x; j < 512; j += blockDim.x) hh[j] = 0;
    __syncthreads();
    const int stride = NBLK3 * 256;
    for (int i = blockIdx.x * blockDim.x + threadIdx.x; i < N_EDGES; i += stride) {
        float lg = logits[i];
        float2 dd = nd[head[i]];   // (denom, deg); 1.6MB -> cached
        float score = __expf(lg) / dd.x * dd.y;
        out_scores[i] = score;
        float noise = -logf(-logf(noise_u[i]));   // library logf: accurate near u->1
        unsigned k = fkey(score + noise);
        keysE[i] = k;
        atomicAdd(&hh[k >> 24], 1u);
        if (i < N_ITEMS) {
            unsigned ki = fkey(sumhead[i] + sumI[i]);
            keysI[i] = ki;
            atomicAdd(&hh[256 + (ki >> 24)], 1u);
        }
    }
    __syncthreads();
    for (int j = threadIdx.x; j < 512; j += blockDim.x) {
        unsigned v = hh[j];
        if (v) atomicAdd(&hists[j], v);   // non-returning global atomic: free (r7)
    }
}

// ---- collect candidates >= 8-bit (sign+exponent) threshold ----
__global__ void collect_kernel(const unsigned* __restrict__ keysE,
                               const unsigned* __restrict__ keysI,
                               const unsigned* __restrict__ hists,
                               unsigned* __restrict__ counters, unsigned* __restrict__ cand) {
    const int y = blockIdx.y;
    const unsigned* keys = y ? keysI : keysE;
    const int n = y ? N_ITEMS : N_EDGES;
    const unsigned K = y ? K_ITEMS : K_EDGES;
    const unsigned* H = hists + (size_t)y * 256;
    unsigned aboveA;
    unsigned binA = select_digit(H, K, &aboveA);
    const unsigned T = binA << 24;
    unsigned* cd = cand + (size_t)y * 2 * CAND_CAP;

    int i = blockIdx.x * blockDim.x + threadIdx.x;
    int stride = gridDim.x * blockDim.x;
    for (; i < n; i += stride) {
        unsigned k = keys[i];
        if (k >= T) {
            unsigned p = atomicAdd(&counters[y], 1u);   // rare (~1.6k total): fine
            if (p < (unsigned)CAND_CAP) { cd[2 * p] = k; cd[2 * p + 1] = (unsigned)i; }
        }
    }
}

// ---- exact rank among candidates (key desc, index asc); 2 blocks (y) ----
__global__ void final_topk_kernel(const unsigned* __restrict__ cand,
                                  const unsigned* __restrict__ counters,
                                  float* __restrict__ out_topkv, float* __restrict__ out_topki,
                                  float* __restrict__ out_itemv, float* __restrict__ out_itemi) {
    __shared__ unsigned sk[CAND_CAP];
    __shared__ unsigned si[CAND_CAP];
    const int y = blockIdx.x;
    const int K = y ? K_ITEMS : K_EDGES;
    float* outv = y ? out_itemv : out_topkv;
    float* outi = y ? out_itemi : out_topki;
    const unsigned* cd = cand + (size_t)y * 2 * CAND_CAP;
    unsigned m = counters[y];
    if (m > (unsigned)CAND_CAP) m = CAND_CAP;
    for (unsigned i = threadIdx.x; i < m; i += blockDim.x) {
        sk[i] = cd[2 * i];
        si[i] = cd[2 * i + 1];
    }
    __syncthreads();
    for (unsigned i = threadIdx.x; i < m; i += blockDim.x) {
        unsigned ki = sk[i], xi = si[i];
        int r = 0;
        for (unsigned j = 0; j < m; ++j) {
            unsigned kj = sk[j];
            if (kj > ki || (kj == ki && si[j] < xi)) r++;
        }
        if (r < K) {
            outv[r] = funkey(ki);
            outi[r] = (float)xi;
        }
    }
}

extern "C" void kernel_launch(void* const* d_in, const int* in_sizes, int n_in,
                              void* d_out, int out_size, void* d_ws, size_t ws_size,
                              hipStream_t stream) {
    (void)in_sizes; (void)n_in; (void)out_size; (void)ws_size;
    const float* emb    = (const float*)d_in[0];
    const float* W      = (const float*)d_in[1];
    const float* rel    = (const float*)d_in[2];
    const float* noise  = (const float*)d_in[3];
    const int*   eidx   = (const int*)d_in[4];
    const int*   etype  = (const int*)d_in[5];
    const int* head = eidx;
    const int* tail = eidx + N_EDGES;

    float* out        = (float*)d_out;
    float* out_scores = out;
    float* out_topkv  = out + N_EDGES;
    float* out_topki  = out + N_EDGES + K_EDGES;
    float* out_itemv  = out + N_EDGES + 2 * K_EDGES;
    float* out_itemi  = out + N_EDGES + 2 * K_EDGES + K_ITEMS;

    float* ws = (float*)d_ws;
    size_t o = 0;
    float*    proj    = ws + o;               o += (size_t)N_ENTITIES * DIM;
    unsigned* off     = (unsigned*)(ws + o);  o += NSC;
    unsigned* bsum    = (unsigned*)(ws + o);  o += 1024;
    u64*      rec2    = (u64*)(ws + o);       o += 2 * (size_t)N_EDGES;   // bucket-major
    unsigned* keysE   = (unsigned*)rec2;      // rec2 dead after csrnode
    unsigned* keysI   = keysE + N_EDGES;
    float*    logits  = ws + o;               o += N_EDGES;
    float2*   nd      = (float2*)(ws + o);    o += 2 * (size_t)N_ENTITIES;
    float*    sumhead = ws + o;               o += N_ENTITIES;
    float*    sumI    = ws + o;               o += N_ITEMS;      // memset begins
    unsigned* hists   = (unsigned*)(ws + o);  o += 512;
    unsigned* counters= (unsigned*)(ws + o);  o += 2;            // memset ends
    unsigned* cand    = (unsigned*)(ws + o);  o += 2 * 2 * CAND_CAP;

    // zero: sumI + hists + counters (contiguous, ~0.4MB)
    hipMemsetAsync(sumI, 0, ((size_t)N_ITEMS + 512 + 2) * 4, stream);
    // fused proj GEMM + bucket histogram (independent; grid-split)
    hipLaunchKernelGGL(proj_bhist_kernel, dim3(PROJB + NB1), dim3(256), 0, stream,
                       emb, W, proj, head, off);
    // exclusive scan of the [NBUCK][NB1] partial-count matrix
    hipLaunchKernelGGL(scanA_kernel, dim3(NSC / 256), dim3(256), 0, stream, off, bsum);
    hipLaunchKernelGGL(scanB_kernel, dim3(NSC / 256), dim3(256), 0, stream, bsum, off);
    // level-1 scatter to bucket-major order
    hipLaunchKernelGGL(bscat_kernel, dim3(NB1), dim3(256), 0, stream,
                       head, tail, etype, off, rec2);
    // FUSED level-2 CSR + node pass (782 blocks; CSR lives only in LDS)
    hipLaunchKernelGGL(csrnode_kernel, dim3(NBUCK), dim3(256), 0, stream,
                       rec2, off, (const float4*)proj, (const float4*)rel,
                       logits, nd, sumhead, sumI);
    // scores + noisy keys + item keys + hist (LDS + free atomic flush)
    hipLaunchKernelGGL(edge_pass3, dim3(NBLK3), dim3(256), 0, stream,
                       logits, head, nd, noise, sumhead, sumI,
                       out_scores, keysE, keysI, hists);
    // top-k: single 8-bit threshold collect + exact rank
    hipLaunchKernelGGL(collect_kernel, dim3(512, 2), dim3(256), 0, stream,
                       keysE, keysI, hists, counters, cand);
    hipLaunchKernelGGL(final_topk_kernel, dim3(2), dim3(1024), 0, stream,
                       cand, counters, out_topkv, out_topki, out_itemv, out_itemi);
}

// Round 13
// 421.926 us; speedup vs baseline: 3.4754x; 1.0216x over previous
//
#include <hip/hip_runtime.h>

#define N_ENTITIES 200000
#define N_ITEMS    100000
#define DIM        64
#define N_EDGES    1500000
#define K_EDGES    256
#define K_ITEMS    100
// 1 / (2 * sqrt(32))  (mean over 2 heads of per-head 1/sqrt(Dk))
#define SCALE      0.08838834764831845f

#define CAND_CAP   8192
#define NBLK3      1024      // edge_pass3 grid
#define NB1        256       // level-1 virtual blocks
#define EPB        5860      // edges per virtual block (256*5860 >= 1.5M)
#define BSH        8         // bucket shift: head>>8 (256 entities/bucket)
#define NBUCK      782       // ceil(200000/256)
#define NSC        (NBUCK * NB1)   // 200192, exactly 782*256
#define QSH        6         // quarter: 64 entities
#define QCAP       768       // max edges/quarter (mean 480 + 13 sigma; r11-proven)
#define PROJB      12500     // proj GEMM blocks (200000/16)

typedef unsigned long long u64;

// NOTE (round-0): fp16/bf16 storage of proj is FORBIDDEN (ordered top-100 item
// list; adjacent gaps ~8e-6; fp16 error 2.7e-6 -> rank flips). f32 only.
// NOTE (rounds 3-8, atomic saga): gfx950 global atomics execute memory-side
// regardless of scope/sc-bits. NON-RETURNING atomics are FREE (r7). RETURNING
// global atomics drain ~50ns each (1.5M = ~75us). Ranks belong in LDS atomics.
// NOTE (r8/r9): node-major CSR is the right shape (293MB @ ~3TB/s random-
// gather ceiling); edge-centric = 467MB = 160us.
// NOTE (r10): persistent kernel + agent-scope spin barriers = 3.4x REGRESSION.
// NOTE (r11/r12): bucket granularity trade RESOLVED by decoupling:
//   - BUILD at 782 buckets (bscat: dense ~60B write runs, 6KB LDS; small scans)
//   - PROCESS at 3128 quarter-buckets (csrnode: 7KB LDS, 12 blocks/CU --
//     r12's 782-block grid gave only 3 blocks/CU = 29% occupancy, the whole
//     regression). Quarter blocks filter the L2/L3-hot bucket region (~15KB)
//     twice; ~94MB cache-resident re-reads ~= 3us.

// ---- monotonic float<->u32 key (order-preserving, total order) ----
__device__ __forceinline__ unsigned fkey(float x) {
    unsigned u = __float_as_uint(x);
    return (u & 0x80000000u) ? ~u : (u | 0x80000000u);
}
__device__ __forceinline__ float funkey(unsigned k) {
    return (k & 0x80000000u) ? __uint_as_float(k & 0x7fffffffu)
                             : __uint_as_float(~k);
}

// serial 256-bin select: largest bin b with count(>b) < Keff <= count(>=b).
__device__ __forceinline__ unsigned select_digit(const unsigned* __restrict__ hist,
                                                 unsigned Keff, unsigned* above) {
    unsigned cum = 0;
    int b = 255;
    for (; b > 0; --b) {
        unsigned hb = hist[b];
        if (cum + hb >= Keff) break;
        cum += hb;
    }
    *above = cum;
    return (unsigned)b;
}

// ---- fused proj GEMM + level-1 bucket histogram (independent work,
// grid-split: blocks < PROJB do GEMM, the rest do the histogram). ----
__global__ __launch_bounds__(256) void proj_bhist_kernel(const float* __restrict__ emb,
                                                         const float* __restrict__ W,
                                                         float* __restrict__ proj,
                                                         const int* __restrict__ head,
                                                         unsigned* __restrict__ off) {
    __shared__ float part[4][16][64];   // 16KB; aliased by the bhist branch
    const int t = threadIdx.x;

    if (blockIdx.x >= PROJB) {
        // ---- bhist branch (256 blocks) ----
        unsigned* lh = (unsigned*)&part[0][0][0];   // NBUCK=782 -> 3.1KB
        const int vb = blockIdx.x - PROJB;
        for (int k = t; k < NBUCK; k += 256) lh[k] = 0;
        __syncthreads();
        int base = vb * EPB;
        int end = base + EPB; if (end > N_EDGES) end = N_EDGES;
        for (int e = base + t; e < end; e += 256)
            atomicAdd(&lh[(unsigned)head[e] >> BSH], 1u);   // LDS atomic: cheap
        __syncthreads();
        for (int k = t; k < NBUCK; k += 256)
            off[(size_t)k * NB1 + vb] = lh[k];
        return;
    }

    // ---- GEMM branch ----
    const int c = t & 63;
    const int q = __builtin_amdgcn_readfirstlane(t >> 6);

    float Wreg[16];
#pragma unroll
    for (int j = 0; j < 16; ++j) Wreg[j] = W[(q * 16 + j) * 64 + c];

    const int base = blockIdx.x * 16;   // 200000 = 12500 * 16, exact
    const float* erow = emb + (size_t)base * 64 + q * 16;

    float acc[16];
#pragma unroll
    for (int r = 0; r < 16; ++r) acc[r] = 0.f;
#pragma unroll
    for (int r = 0; r < 16; ++r) {
#pragma unroll
        for (int j = 0; j < 16; ++j)
            acc[r] += erow[r * 64 + j] * Wreg[j];
    }
#pragma unroll
    for (int r = 0; r < 16; ++r) part[q][r][c] = acc[r];
    __syncthreads();
#pragma unroll
    for (int it = 0; it < 4; ++it) {
        int oi = t + it * 256;
        int r = oi >> 6, cc = oi & 63;
        float s = part[0][r][cc] + part[1][r][cc] + part[2][r][cc] + part[3][r][cc];
        proj[(size_t)(base + r) * 64 + cc] = s;
    }
}

// ---- hierarchical exclusive scan over NSC elements (in place) ----
__global__ void scanA_kernel(unsigned* __restrict__ a, unsigned* __restrict__ bsum) {
    __shared__ unsigned s[256];
    int t = threadIdx.x, i = blockIdx.x * 256 + t;
    unsigned v = a[i];                  // NSC exactly divisible, no bounds check
    s[t] = v;
    __syncthreads();
    for (int off = 1; off < 256; off <<= 1) {
        unsigned x = s[t];
        unsigned y = (t >= off) ? s[t - off] : 0u;
        __syncthreads();
        s[t] = x + y;
        __syncthreads();
    }
    a[i] = s[t] - v;                    // block-local exclusive
    if (t == 255) bsum[blockIdx.x] = s[t];
}
__global__ __launch_bounds__(256) void scanB_kernel(const unsigned* __restrict__ bsum,
                                                    unsigned* __restrict__ a) {
    __shared__ unsigned part[4];
    const int b = blockIdx.x;
    const int t = threadIdx.x;
    unsigned s = 0;
    for (int j = t; j < b; j += 256) s += bsum[j];
#pragma unroll
    for (int off = 1; off < 64; off <<= 1) s += __shfl_xor(s, off, 64);
    if ((t & 63) == 0) part[t >> 6] = s;
    __syncthreads();
    unsigned prefix = part[0] + part[1] + part[2] + part[3];
    a[b * 256 + t] += prefix;
}

// ---- level-1 scatter: edges -> bucket-major rec2 (ranks via LDS atomics) ----
// rec = head(18b)<<45 | tail(18b)<<27 | rel(6b)<<21 | eid(21b)
// 782 buckets: ~7.5 edges/bucket/vblock -> ~60B write runs (dense; r11 lesson)
__global__ __launch_bounds__(256) void bscat_kernel(const int* __restrict__ head,
                                                    const int* __restrict__ tail,
                                                    const int* __restrict__ etype,
                                                    const unsigned* __restrict__ off,
                                                    u64* __restrict__ rec2) {
    __shared__ unsigned lh[NBUCK];
    __shared__ unsigned loff[NBUCK];
    for (int k = threadIdx.x; k < NBUCK; k += 256) {
        lh[k] = 0;
        loff[k] = off[(size_t)k * NB1 + blockIdx.x];
    }
    __syncthreads();
    int base = blockIdx.x * EPB;
    int end = base + EPB; if (end > N_EDGES) end = N_EDGES;
    for (int e = base + threadIdx.x; e < end; e += 256) {
        unsigned h = (unsigned)head[e];
        unsigned bkt = h >> BSH;
        unsigned r = atomicAdd(&lh[bkt], 1u);          // LDS returning atomic: cheap
        u64 R = ((u64)h << 45) | ((u64)(unsigned)tail[e] << 27)
              | ((u64)(unsigned)(etype[e] - 1) << 21) | (u64)(unsigned)e;
        rec2[loff[bkt] + r] = R;
    }
}

// ---- FUSED quarter-bucket CSR + node pass (3128 blocks, 64 entities each).
// Each block filters its quarter out of the bucket's (L2-hot) record region,
// builds the quarter CSR in 7KB LDS, runs the node pass straight from LDS.
__global__ __launch_bounds__(256) void csrnode_kernel(const u64* __restrict__ rec2,
                                                      const unsigned* __restrict__ off,
                                                      const float4* __restrict__ proj4,
                                                      const float4* __restrict__ rel4,
                                                      float* __restrict__ logits,
                                                      float2* __restrict__ nd,
                                                      float* __restrict__ sumhead,
                                                      float* __restrict__ sumI) {
    __shared__ u64 sdst[QCAP];        // 6KB
    __shared__ unsigned lh[64];
    __shared__ unsigned lscan[64];
    __shared__ unsigned lcur[64];
    const int t = threadIdx.x;
    const int bkt = blockIdx.x >> 2;
    const unsigned q = blockIdx.x & 3u;
    const unsigned gstart = off[(size_t)bkt * NB1];
    const unsigned gend = (bkt == NBUCK - 1) ? (unsigned)N_EDGES
                                             : off[(size_t)(bkt + 1) * NB1];
    const unsigned n = gend - gstart;
    if (t < 64) lh[t] = 0;
    __syncthreads();
    // pass A: count this quarter's per-entity degrees (region is L2/L3-hot)
    for (unsigned j = t; j < n; j += 256) {
        unsigned hl = (unsigned)(rec2[gstart + j] >> 45) & 255u;
        if ((hl >> QSH) == q) atomicAdd(&lh[hl & 63u], 1u);
    }
    __syncthreads();
    // exclusive scan of 64 counts
    unsigned v0 = (t < 64) ? lh[t] : 0u;
    if (t < 64) lscan[t] = v0;
    __syncthreads();
    for (int o = 1; o < 64; o <<= 1) {
        unsigned x = 0, y = 0;
        if (t < 64) { x = lscan[t]; y = (t >= o) ? lscan[t - o] : 0u; }
        __syncthreads();
        if (t < 64) lscan[t] = x + y;
        __syncthreads();
    }
    if (t < 64) {
        unsigned ex = lscan[t] - v0;
        lscan[t] = ex;
        lcur[t] = ex;
    }
    __syncthreads();
    // pass B: scatter quarter's records into CSR order in LDS (ranks = fresh
    // LDS atomic arrival order; no srank array needed)
    for (unsigned j = t; j < n; j += 256) {
        u64 R = rec2[gstart + j];
        unsigned hl = (unsigned)(R >> 45) & 255u;
        if ((hl >> QSH) == q) {
            unsigned d = atomicAdd(&lcur[hl & 63u], 1u);
            if (d < QCAP) sdst[d] = R;   // statistically always true (+13 sigma)
        }
    }
    __syncthreads();

    // node phase: wave wv handles 16 nodes; per-node math/order identical to
    // r9's node_pass (bit-identical per-node sums).
    const int lane = t & 63;
    const int wv = t >> 6;
    const int slot = lane >> 4, sl = lane & 15;
    for (int ln = 0; ln < 16; ++ln) {
        const int local = wv * 16 + ln;                       // 0..63
        const int node = (bkt << BSH) + ((int)q << QSH) + local;
        if (node >= N_ENTITIES) break;   // partial last bucket (200192 > 200000)
        const unsigned s0 = lscan[local];
        const unsigned len = lh[local];
        float4 ph = proj4[(size_t)node * 16 + sl];
        float dsum = 0.f, lsum = 0.f;
        for (unsigned k0 = 0; k0 < len; k0 += 8) {
            unsigned ka = k0 + slot, kb = ka + 4;
            bool va = (ka < len), vb = (kb < len);
            u64 Ra = sdst[s0 + (va ? ka : 0u)];
            u64 Rb = sdst[s0 + (vb ? kb : 0u)];
            unsigned ta = (unsigned)(Ra >> 27) & 0x3FFFFu, ria = ((unsigned)(Ra >> 21)) & 63u;
            unsigned tb = (unsigned)(Rb >> 27) & 0x3FFFFu, rib = ((unsigned)(Rb >> 21)) & 63u;
            unsigned ea = (unsigned)Ra & 0x1FFFFFu, eb = (unsigned)Rb & 0x1FFFFFu;
            float4 pa = proj4[(size_t)ta * 16 + sl];
            float4 qa = rel4[(size_t)ria * 16 + sl];
            float4 pb = proj4[(size_t)tb * 16 + sl];
            float4 qb = rel4[(size_t)rib * 16 + sl];
            float xa = ph.x * pa.x * qa.x + ph.y * pa.y * qa.y
                     + ph.z * pa.z * qa.z + ph.w * pa.w * qa.w;
            float xb = ph.x * pb.x * qb.x + ph.y * pb.y * qb.y
                     + ph.z * pb.z * qb.z + ph.w * pb.w * qb.w;
            xa += __shfl_xor(xa, 1, 64);  xb += __shfl_xor(xb, 1, 64);
            xa += __shfl_xor(xa, 2, 64);  xb += __shfl_xor(xb, 2, 64);
            xa += __shfl_xor(xa, 4, 64);  xb += __shfl_xor(xb, 4, 64);
            xa += __shfl_xor(xa, 8, 64);  xb += __shfl_xor(xb, 8, 64);
            if (sl == 0) {
                if (va) {
                    float lg = xa * SCALE;
                    logits[ea] = lg;
                    dsum += __expf(lg);
                    lsum += lg;
                    if (ta < N_ITEMS) atomicAdd(&sumI[ta], lg);   // non-returning: free
                }
                if (vb) {
                    float lg = xb * SCALE;
                    logits[eb] = lg;
                    dsum += __expf(lg);
                    lsum += lg;
                    if (tb < N_ITEMS) atomicAdd(&sumI[tb], lg);
                }
            }
        }
        dsum += __shfl_xor(dsum, 16, 64);
        dsum += __shfl_xor(dsum, 32, 64);
        lsum += __shfl_xor(lsum, 16, 64);
        lsum += __shfl_xor(lsum, 32, 64);
        if (lane == 0) {
            nd[node] = make_float2(dsum, (float)len);
            sumhead[node] = lsum;
        }
    }
}

// ---- scores + gumbel keys + item keys; LDS hist, non-returning atomic flush ----
__global__ __launch_bounds__(256) void edge_pass3(const float* __restrict__ logits,
                           const int* __restrict__ head,
                           const float2* __restrict__ nd, const float* __restrict__ noise_u,
                           const float* __restrict__ sumhead, const float* __restrict__ sumI,
                           float* __restrict__ out_scores, unsigned* __restrict__ keysE,
                           unsigned* __restrict__ keysI, unsigned* __restrict__ hists) {
    __shared__ unsigned hh[512];   // [0..255]=edge bins, [256..511]=item bins
    for (int j = threadIdx.x; j < 512; j += blockDim.x) hh[j] = 0;
    __syncthreads();
    const int stride = NBLK3 * 256;
    for (int i = blockIdx.x * blockDim.x + threadIdx.x; i < N_EDGES; i += stride) {
        float lg = logits[i];
        float2 dd = nd[head[i]];   // (denom, deg); 1.6MB -> cached
        float score = __expf(lg) / dd.x * dd.y;
        out_scores[i] = score;
        float noise = -logf(-logf(noise_u[i]));   // library logf: accurate near u->1
        unsigned k = fkey(score + noise);
        keysE[i] = k;
        atomicAdd(&hh[k >> 24], 1u);
        if (i < N_ITEMS) {
            unsigned ki = fkey(sumhead[i] + sumI[i]);
            keysI[i] = ki;
            atomicAdd(&hh[256 + (ki >> 24)], 1u);
        }
    }
    __syncthreads();
    for (int j = threadIdx.x; j < 512; j += blockDim.x) {
        unsigned v = hh[j];
        if (v) atomicAdd(&hists[j], v);   // non-returning global atomic: free (r7)
    }
}

// ---- collect candidates >= 8-bit (sign+exponent) threshold ----
__global__ void collect_kernel(const unsigned* __restrict__ keysE,
                               const unsigned* __restrict__ keysI,
                               const unsigned* __restrict__ hists,
                               unsigned* __restrict__ counters, unsigned* __restrict__ cand) {
    const int y = blockIdx.y;
    const unsigned* keys = y ? keysI : keysE;
    const int n = y ? N_ITEMS : N_EDGES;
    const unsigned K = y ? K_ITEMS : K_EDGES;
    const unsigned* H = hists + (size_t)y * 256;
    unsigned aboveA;
    unsigned binA = select_digit(H, K, &aboveA);
    const unsigned T = binA << 24;
    unsigned* cd = cand + (size_t)y * 2 * CAND_CAP;

    int i = blockIdx.x * blockDim.x + threadIdx.x;
    int stride = gridDim.x * blockDim.x;
    for (; i < n; i += stride) {
        unsigned k = keys[i];
        if (k >= T) {
            unsigned p = atomicAdd(&counters[y], 1u);   // rare (~1.6k total): fine
            if (p < (unsigned)CAND_CAP) { cd[2 * p] = k; cd[2 * p + 1] = (unsigned)i; }
        }
    }
}

// ---- exact rank among candidates (key desc, index asc); 2 blocks (y) ----
__global__ void final_topk_kernel(const unsigned* __restrict__ cand,
                                  const unsigned* __restrict__ counters,
                                  float* __restrict__ out_topkv, float* __restrict__ out_topki,
                                  float* __restrict__ out_itemv, float* __restrict__ out_itemi) {
    __shared__ unsigned sk[CAND_CAP];
    __shared__ unsigned si[CAND_CAP];
    const int y = blockIdx.x;
    const int K = y ? K_ITEMS : K_EDGES;
    float* outv = y ? out_itemv : out_topkv;
    float* outi = y ? out_itemi : out_topki;
    const unsigned* cd = cand + (size_t)y * 2 * CAND_CAP;
    unsigned m = counters[y];
    if (m > (unsigned)CAND_CAP) m = CAND_CAP;
    for (unsigned i = threadIdx.x; i < m; i += blockDim.x) {
        sk[i] = cd[2 * i];
        si[i] = cd[2 * i + 1];
    }
    __syncthreads();
    for (unsigned i = threadIdx.x; i < m; i += blockDim.x) {
        unsigned ki = sk[i], xi = si[i];
        int r = 0;
        for (unsigned j = 0; j < m; ++j) {
            unsigned kj = sk[j];
            if (kj > ki || (kj == ki && si[j] < xi)) r++;
        }
        if (r < K) {
            outv[r] = funkey(ki);
            outi[r] = (float)xi;
        }
    }
}

extern "C" void kernel_launch(void* const* d_in, const int* in_sizes, int n_in,
                              void* d_out, int out_size, void* d_ws, size_t ws_size,
                              hipStream_t stream) {
    (void)in_sizes; (void)n_in; (void)out_size; (void)ws_size;
    const float* emb    = (const float*)d_in[0];
    const float* W      = (const float*)d_in[1];
    const float* rel    = (const float*)d_in[2];
    const float* noise  = (const float*)d_in[3];
    const int*   eidx   = (const int*)d_in[4];
    const int*   etype  = (const int*)d_in[5];
    const int* head = eidx;
    const int* tail = eidx + N_EDGES;

    float* out        = (float*)d_out;
    float* out_scores = out;
    float* out_topkv  = out + N_EDGES;
    float* out_topki  = out + N_EDGES + K_EDGES;
    float* out_itemv  = out + N_EDGES + 2 * K_EDGES;
    float* out_itemi  = out + N_EDGES + 2 * K_EDGES + K_ITEMS;

    float* ws = (float*)d_ws;
    size_t o = 0;
    float*    proj    = ws + o;               o += (size_t)N_ENTITIES * DIM;
    unsigned* off     = (unsigned*)(ws + o);  o += NSC;
    unsigned* bsum    = (unsigned*)(ws + o);  o += 1024;
    u64*      rec2    = (u64*)(ws + o);       o += 2 * (size_t)N_EDGES;   // bucket-major
    unsigned* keysE   = (unsigned*)rec2;      // rec2 dead after csrnode
    unsigned* keysI   = keysE + N_EDGES;
    float*    logits  = ws + o;               o += N_EDGES;
    float2*   nd      = (float2*)(ws + o);    o += 2 * (size_t)N_ENTITIES;
    float*    sumhead = ws + o;               o += N_ENTITIES;
    float*    sumI    = ws + o;               o += N_ITEMS;      // memset begins
    unsigned* hists   = (unsigned*)(ws + o);  o += 512;
    unsigned* counters= (unsigned*)(ws + o);  o += 2;            // memset ends
    unsigned* cand    = (unsigned*)(ws + o);  o += 2 * 2 * CAND_CAP;

    // zero: sumI + hists + counters (contiguous, ~0.4MB)
    hipMemsetAsync(sumI, 0, ((size_t)N_ITEMS + 512 + 2) * 4, stream);
    // fused proj GEMM + bucket histogram (independent; grid-split)
    hipLaunchKernelGGL(proj_bhist_kernel, dim3(PROJB + NB1), dim3(256), 0, stream,
                       emb, W, proj, head, off);
    // exclusive scan of the [NBUCK][NB1] partial-count matrix
    hipLaunchKernelGGL(scanA_kernel, dim3(NSC / 256), dim3(256), 0, stream, off, bsum);
    hipLaunchKernelGGL(scanB_kernel, dim3(NSC / 256), dim3(256), 0, stream, bsum, off);
    // level-1 scatter to bucket-major order (782 buckets: dense writes)
    hipLaunchKernelGGL(bscat_kernel, dim3(NB1), dim3(256), 0, stream,
                       head, tail, etype, off, rec2);
    // FUSED quarter-bucket CSR + node pass (3128 blocks; 7KB LDS; full grid)
    hipLaunchKernelGGL(csrnode_kernel, dim3(NBUCK * 4), dim3(256), 0, stream,
                       rec2, off, (const float4*)proj, (const float4*)rel,
                       logits, nd, sumhead, sumI);
    // scores + noisy keys + item keys + hist (LDS + free atomic flush)
    hipLaunchKernelGGL(edge_pass3, dim3(NBLK3), dim3(256), 0, stream,
                       logits, head, nd, noise, sumhead, sumI,
                       out_scores, keysE, keysI, hists);
    // top-k: single 8-bit threshold collect + exact rank
    hipLaunchKernelGGL(collect_kernel, dim3(512, 2), dim3(256), 0, stream,
                       keysE, keysI, hists, counters, cand);
    hipLaunchKernelGGL(final_topk_kernel, dim3(2), dim3(1024), 0, stream,
                       cand, counters, out_topkv, out_topki, out_itemv, out_itemi);
}